// Round 7
// baseline (169.864 us; speedup 1.0000x reference)
//
#include <hip/hip_runtime.h>
#include <hip/hip_bf16.h>
#include <hip/hip_fp16.h>
#include <math.h>

// Decoder: out[e] = sigmoid(relu( W2 . relu( W1 * [x[src]; x[dst]] + b1 ) + b2 ))
// Factorized: Y[n][0:128] = W1_left*x[n] + b1 ; Y[n][128:256] = W1_right*x[n]
//             out[e] = sigmoid(relu( W2 . relu(Yl[src]+Yr[dst]) + b2 ))
// R7: (a) precompute grid transposed -> 4 col-slice blocks of the same node
//     tile are dispatch-adjacent, x fetched once (R6 FETCH showed x read 2x
//     from HBM with the slice-major order).
//     (b) edge kernel: packed fp16 (v_pk_add_f16 + bitmask relu + v_dot2),
//     2 edges per 8-lane group with all gathers issued up front (2x MLP).

typedef short    s16x4 __attribute__((ext_vector_type(4)));
typedef short    s16x8 __attribute__((ext_vector_type(8)));
typedef float    f32x4 __attribute__((ext_vector_type(4)));
typedef _Float16 h16x2 __attribute__((ext_vector_type(2)));
typedef _Float16 h16x8 __attribute__((ext_vector_type(8)));

#define D    128
#define CWLD 80        // LDS transpose row stride (shorts)

static __device__ inline short f2bf(float f) {
    unsigned u = __builtin_bit_cast(unsigned, f);
    unsigned r = (u + 0x7FFFu + ((u >> 16) & 1u)) >> 16;
    return (short)r;
}

static __device__ inline h16x2 relu2(h16x2 v) {
    unsigned u = __builtin_bit_cast(unsigned, v);
    unsigned m = ((u >> 15) & 0x00010001u) * 0xFFFFu;   // per-half sign mask
    u &= ~m;
    return __builtin_bit_cast(h16x2, u);
}

static __device__ inline float dot2acc(h16x2 a, h16x2 b, float c) {
#if __has_builtin(__builtin_amdgcn_fdot2)
    return __builtin_amdgcn_fdot2(a, b, c, false);
#else
    return c + (float)a[0] * (float)b[0] + (float)a[1] * (float)b[1];
#endif
}

// ---------------- pack W1 -> bf16 fragment order ----------------
__global__ __launch_bounds__(256) void pack_w1_kernel(
    const float* __restrict__ W1, short* __restrict__ W1F)
{
    int g    = blockIdx.x * 256 + threadIdx.x;   // 0..4095
    int lane = g & 63;
    int c    = (g >> 6) & 3;
    int j    = (g >> 8) & 3;
    int cs   = g >> 10;
    int o    = cs * 64 + j * 16 + (lane & 15);
    int kb   = c * 32 + (lane >> 4) * 8;
    const float* wp = W1 + (size_t)(o & 127) * 256 + (o >> 7) * 128 + kb;
    float4 u0 = *(const float4*)wp;
    float4 u1 = *(const float4*)(wp + 4);
    s16x8 v = { f2bf(u0.x), f2bf(u0.y), f2bf(u0.z), f2bf(u0.w),
                f2bf(u1.x), f2bf(u1.y), f2bf(u1.z), f2bf(u1.w) };
    *(s16x8*)&W1F[(size_t)g * 8] = v;
}

// ---------------- Phase A: per-wave 32 rows x 64 cols, no barriers ----------------
// grid = (4, N/32): col-slice fastest -> sibling slices of one node tile are
// dispatch-adjacent, x rows L2/L3-hot after the first slice.
__global__ __launch_bounds__(64) void precompute_kernel(
    const float* __restrict__ x,    // [N,128]
    const short* __restrict__ W1F,  // packed bf16 fragments
    const float* __restrict__ b1,   // [128]
    _Float16*    __restrict__ Y,    // [N,256]
    int N)
{
    __shared__ _Float16 Cw[32 * CWLD];   // 5120 B, wave-private

    const int lane = threadIdx.x;        // single wave
    const int quad = lane >> 4, l15 = lane & 15;
    const int cs   = blockIdx.x;         // col slice: cols cs*64 .. +63
    const int m0   = blockIdx.y * 32;

    // ---- A raw loads first (HBM)
    float4 ar[2][4][2];
    #pragma unroll
    for (int i = 0; i < 2; ++i) {
        int m = m0 + i * 16 + l15; if (m >= N) m = N - 1;
        const float* xp = &x[(size_t)m * D + quad * 8];
        #pragma unroll
        for (int c = 0; c < 4; ++c) {
            ar[i][c][0] = *(const float4*)(xp + c * 32);
            ar[i][c][1] = *(const float4*)(xp + c * 32 + 4);
        }
    }

    // ---- B frags: coalesced 16B/lane from W1F (L2-hot)
    s16x8 bf[4][4];   // [k-chunk][col-tile]
    #pragma unroll
    for (int j = 0; j < 4; ++j)
        #pragma unroll
        for (int c = 0; c < 4; ++c)
            bf[c][j] = *(const s16x8*)&W1F[(size_t)(((cs * 4 + j) * 4 + c) * 64 + lane) * 8];

    // ---- MFMA
    f32x4 acc[2][4] = {};   // [row-tile][col-tile]
    #pragma unroll
    for (int c = 0; c < 4; ++c) {
        s16x8 af[2];
        #pragma unroll
        for (int i = 0; i < 2; ++i)
            af[i] = (s16x8){ f2bf(ar[i][c][0].x), f2bf(ar[i][c][0].y),
                             f2bf(ar[i][c][0].z), f2bf(ar[i][c][0].w),
                             f2bf(ar[i][c][1].x), f2bf(ar[i][c][1].y),
                             f2bf(ar[i][c][1].z), f2bf(ar[i][c][1].w) };
        #pragma unroll
        for (int i = 0; i < 2; ++i)
            #pragma unroll
            for (int j = 0; j < 4; ++j)
                acc[i][j] = __builtin_amdgcn_mfma_f32_16x16x32_bf16(
                    af[i], bf[c][j], acc[i][j], 0, 0, 0);
    }

    // ---- bias (cs<2 -> left half)
    float b1v[4];
    #pragma unroll
    for (int j = 0; j < 4; ++j)
        b1v[j] = (cs < 2) ? b1[cs * 64 + j * 16 + l15] : 0.f;

    // ---- transpose through wave-private LDS
    // C/D layout: col = lane&15, row = quad*4 + reg
    #pragma unroll
    for (int i = 0; i < 2; ++i)
        #pragma unroll
        for (int j = 0; j < 4; ++j)
            #pragma unroll
            for (int r = 0; r < 4; ++r)
                Cw[(i * 16 + quad * 4 + r) * CWLD + j * 16 + l15] =
                    (_Float16)(acc[i][j][r] + b1v[j]);

    __syncthreads();

    // ---- coalesced store: 8 rows x 128B per pass
    #pragma unroll
    for (int p = 0; p < 4; ++p) {
        int row = p * 8 + (lane >> 3);
        int m   = m0 + row;
        if (m < N) {
            h16x8 v = *(const h16x8*)&Cw[row * CWLD + (lane & 7) * 8];
            *(h16x8*)&Y[(size_t)m * 256 + cs * 64 + (lane & 7) * 8] = v;
        }
    }
}

// ---------------- Phase B: 2 edges per 8-lane group, packed fp16 ----------------
#define EPB 64   // edges per block (256 threads, 32 groups x 2 edges)

__global__ __launch_bounds__(256) void edge_kernel(
    const _Float16* __restrict__ Y,   // [N,256]
    const int*      __restrict__ ei,  // [2,E]
    const float*    __restrict__ W2,  // [128]
    const float*    __restrict__ b2,  // [1]
    float*          __restrict__ out, // [E]
    int E)
{
    const int tid = threadIdx.x;
    const int sub = tid & 7;                    // 8 lanes per edge
    const int grp = tid >> 3;                   // 0..31
    const int eA  = blockIdx.x * EPB + grp;
    const int eB  = eA + 32;

    // W2 as packed fp16 pairs (16 elems for this sub-lane)
    h16x2 w2h[8];
    {
        const float* wp = &W2[sub * 16];
        #pragma unroll
        for (int q = 0; q < 8; ++q) {
            float2 f = *(const float2*)(wp + q * 2);
            w2h[q] = (h16x2){ (_Float16)f.x, (_Float16)f.y };
        }
    }

    bool vA = (eA < E), vB = (eB < E);
    int srcA = vA ? ei[eA] : 0, dstA = vA ? ei[E + eA] : 0;
    int srcB = vB ? ei[eB] : 0, dstB = vB ? ei[E + eB] : 0;

    // issue all 8 gather loads up front
    const _Float16* plA = Y + (size_t)srcA * 256 + sub * 16;
    const _Float16* prA = Y + (size_t)dstA * 256 + 128 + sub * 16;
    const _Float16* plB = Y + (size_t)srcB * 256 + sub * 16;
    const _Float16* prB = Y + (size_t)dstB * 256 + 128 + sub * 16;
    h16x8 a0 = *(const h16x8*)plA;
    h16x8 a1 = *(const h16x8*)(plA + 8);
    h16x8 c0 = *(const h16x8*)prA;
    h16x8 c1 = *(const h16x8*)(prA + 8);
    h16x8 d0 = *(const h16x8*)plB;
    h16x8 d1 = *(const h16x8*)(plB + 8);
    h16x8 g0 = *(const h16x8*)prB;
    h16x8 g1 = *(const h16x8*)(prB + 8);

    float sA = 0.f, sB = 0.f;
    #pragma unroll
    for (int q = 0; q < 4; ++q) {
        h16x2 ra = relu2((h16x2){ a0[q*2], a0[q*2+1] } + (h16x2){ c0[q*2], c0[q*2+1] });
        sA = dot2acc(ra, w2h[q], sA);
        h16x2 rb = relu2((h16x2){ d0[q*2], d0[q*2+1] } + (h16x2){ g0[q*2], g0[q*2+1] });
        sB = dot2acc(rb, w2h[q], sB);
    }
    #pragma unroll
    for (int q = 0; q < 4; ++q) {
        h16x2 ra = relu2((h16x2){ a1[q*2], a1[q*2+1] } + (h16x2){ c1[q*2], c1[q*2+1] });
        sA = dot2acc(ra, w2h[4 + q], sA);
        h16x2 rb = relu2((h16x2){ d1[q*2], d1[q*2+1] } + (h16x2){ g1[q*2], g1[q*2+1] });
        sB = dot2acc(rb, w2h[4 + q], sB);
    }

    // reduce over the 8 lanes of each edge (xor stays within the group)
    sA += __shfl_xor(sA, 1);  sB += __shfl_xor(sB, 1);
    sA += __shfl_xor(sA, 2);  sB += __shfl_xor(sB, 2);
    sA += __shfl_xor(sA, 4);  sB += __shfl_xor(sB, 4);

    if (sub == 0) {
        float bb = b2[0];
        if (vA) {
            float s = fmaxf(sA + bb, 0.f);
            out[eA] = 1.0f / (1.0f + expf(-s));
        }
        if (vB) {
            float s = fmaxf(sB + bb, 0.f);
            out[eB] = 1.0f / (1.0f + expf(-s));
        }
    }
}

// ---------------- fallback (fused edge-wise GEMM, fp32 inputs) ----------------
#define BM   128
#define BK   64
#define LDT  72

__global__ __launch_bounds__(256) void decoder_fallback_kernel(
    const float* __restrict__ x, const int* __restrict__ ei,
    const float* __restrict__ W1, const float* __restrict__ b1,
    const float* __restrict__ W2, const float* __restrict__ b2,
    float* __restrict__ out, int E)
{
    __shared__ int   nid[2][BM];
    __shared__ short At[BM * LDT];
    __shared__ short Bt[D * LDT];
    __shared__ float rowsum[BM][2];

    const int tid = threadIdx.x;
    const int e0  = blockIdx.x * BM;
    if (tid < BM) { int e = e0 + tid; nid[0][tid] = (e < E) ? ei[e] : 0; }
    else { int e = e0 + (tid - BM); nid[1][tid - BM] = (e < E) ? ei[E + e] : 0; }

    const int wid = tid >> 6, lane = tid & 63;
    const int wm = wid >> 1, wn = wid & 1;
    const int quad = lane >> 4, l15 = lane & 15;
    const int srow = tid >> 4, scol = (tid & 15) * 4;
    f32x4 acc[4][4] = {};
    __syncthreads();

    for (int t = 0; t < 4; ++t) {
        const int* ids = nid[t >> 1];
        const int kx = (t & 1) * BK, kw = t * BK;
        #pragma unroll
        for (int p = 0; p < 8; ++p) {
            int row = srow + p * 16;
            float4 v = *(const float4*)&x[(size_t)ids[row] * D + kx + scol];
            s16x4 bv = { f2bf(v.x), f2bf(v.y), f2bf(v.z), f2bf(v.w) };
            *(s16x4*)&At[row * LDT + scol] = bv;
        }
        #pragma unroll
        for (int p = 0; p < 8; ++p) {
            int n = srow + p * 16;
            float4 v = *(const float4*)&W1[n * 256 + kw + scol];
            s16x4 bv = { f2bf(v.x), f2bf(v.y), f2bf(v.z), f2bf(v.w) };
            *(s16x4*)&Bt[n * LDT + scol] = bv;
        }
        __syncthreads();
        #pragma unroll
        for (int c = 0; c < 2; ++c) {
            const int kc = c * 32;
            s16x8 af[4], bfr[4];
            #pragma unroll
            for (int i = 0; i < 4; ++i)
                af[i] = *(const s16x8*)&At[(wm*64 + i*16 + l15) * LDT + kc + quad*8];
            #pragma unroll
            for (int j = 0; j < 4; ++j)
                bfr[j] = *(const s16x8*)&Bt[(wn*64 + j*16 + l15) * LDT + kc + quad*8];
            #pragma unroll
            for (int i = 0; i < 4; ++i)
                #pragma unroll
                for (int j = 0; j < 4; ++j)
                    acc[i][j] = __builtin_amdgcn_mfma_f32_16x16x32_bf16(
                        af[i], bfr[j], acc[i][j], 0, 0, 0);
        }
        __syncthreads();
    }
    float b1v[4], w2v[4];
    #pragma unroll
    for (int j = 0; j < 4; ++j) {
        int col = wn*64 + j*16 + l15;
        b1v[j] = b1[col]; w2v[j] = W2[col];
    }
    float psum[16];
    #pragma unroll
    for (int t = 0; t < 16; ++t) psum[t] = 0.f;
    #pragma unroll
    for (int i = 0; i < 4; ++i)
        #pragma unroll
        for (int j = 0; j < 4; ++j)
            #pragma unroll
            for (int r = 0; r < 4; ++r) {
                float c = fmaxf(acc[i][j][r] + b1v[j], 0.f);
                psum[i*4 + r] += c * w2v[j];
            }
    #pragma unroll
    for (int off = 1; off < 16; off <<= 1)
        #pragma unroll
        for (int t = 0; t < 16; ++t)
            psum[t] += __shfl_xor(psum[t], off);
    if (l15 == 0) {
        #pragma unroll
        for (int i = 0; i < 4; ++i)
            #pragma unroll
            for (int r = 0; r < 4; ++r)
                rowsum[wm*64 + i*16 + quad*4 + r][wn] = psum[i*4 + r];
    }
    __syncthreads();
    if (tid < BM) {
        int e = e0 + tid;
        if (e < E) {
            float s = rowsum[tid][0] + rowsum[tid][1] + b2[0];
            s = fmaxf(s, 0.f);
            out[e] = 1.0f / (1.0f + expf(-s));
        }
    }
}

extern "C" void kernel_launch(void* const* d_in, const int* in_sizes, int n_in,
                              void* d_out, int out_size, void* d_ws, size_t ws_size,
                              hipStream_t stream) {
    const float* x  = (const float*)d_in[0];
    const int*   ei = (const int*)d_in[1];
    const float* W1 = (const float*)d_in[2];
    const float* b1 = (const float*)d_in[3];
    const float* W2 = (const float*)d_in[4];
    const float* b2 = (const float*)d_in[5];
    float* out = (float*)d_out;

    int E = in_sizes[1] / 2;
    int N = in_sizes[0] / D;

    size_t y_bytes = (size_t)N * 256 * sizeof(_Float16);       // 51.2 MB
    size_t need    = y_bytes + 32768 * sizeof(short);          // + 64 KB W1F
    if (ws_size >= need) {
        _Float16* Y   = (_Float16*)d_ws;
        short*    W1F = (short*)((char*)d_ws + y_bytes);
        pack_w1_kernel<<<16, 256, 0, stream>>>(W1, W1F);
        dim3 gridA(4, (N + 31) / 32);
        precompute_kernel<<<gridA, 64, 0, stream>>>(x, W1F, b1, Y, N);
        int gridB = (E + EPB - 1) / EPB;
        edge_kernel<<<gridB, 256, 0, stream>>>(Y, ei, W2, b2, out, E);
    } else {
        int nblocks = (E + BM - 1) / BM;
        decoder_fallback_kernel<<<nblocks, 256, 0, stream>>>(
            x, ei, W1, b1, W2, b2, out, E);
    }
}

// Round 8
// 151.821 us; speedup vs baseline: 1.1188x; 1.1188x over previous
//
#include <hip/hip_runtime.h>
#include <hip/hip_bf16.h>
#include <hip/hip_fp16.h>
#include <math.h>

// Decoder: out[e] = sigmoid(relu( W2 . relu( W1 * [x[src]; x[dst]] + b1 ) + b2 ))
// Factorized: Y[n][0:128] = W1_left*x[n] + b1 ; Y[n][128:256] = W1_right*x[n]
//             out[e] = sigmoid(relu( W2 . relu(Yl[src]+Yr[dst]) + b2 ))
// R8: Y stored as OCP fp8 e4m3 (25.6 MB). R7 showed every kernel plateaus at
//     ~3.4 TB/s L2-fill; the only lever left is bytes. fp8 halves the edge
//     gather (1 cache line per half-row) and the precompute write.
//     Decode: HW v_cvt_pk_f16_fp8 if available, else exact integer trick
//     (e4m3 bits<<7 = fp16 bits of value/256; the /256 is folded into W2).

typedef short    s16x4 __attribute__((ext_vector_type(4)));
typedef short    s16x8 __attribute__((ext_vector_type(8)));
typedef float    f32x4 __attribute__((ext_vector_type(4)));
typedef _Float16 h16x2 __attribute__((ext_vector_type(2)));
typedef _Float16 h16x8 __attribute__((ext_vector_type(8)));

#define D    128
#define CWLD 80        // LDS transpose row stride (shorts)

static __device__ inline short f2bf(float f) {
    unsigned u = __builtin_bit_cast(unsigned, f);
    unsigned r = (u + 0x7FFFu + ((u >> 16) & 1u)) >> 16;
    return (short)r;
}

// ---------- fp8 e4m3 encode (RNE) ----------
static __device__ inline unsigned enc1_sw(float f) {
    // clamp, then RNE via fp16 with exponent pre-shift (bias 15-8=7 = e4m3 bias)
    f = fminf(fmaxf(f, -448.f), 448.f);
    unsigned short h = __builtin_bit_cast(unsigned short, (_Float16)(f * (1.0f / 256.0f)));
    unsigned s = (h >> 8) & 0x80u;
    unsigned mag = h & 0x7FFFu;
    mag = mag + 0x3Fu + ((mag >> 7) & 1u);        // RNE 10->3 mantissa bits
    return s | ((mag >> 7) & 0x7Fu);
}
static __device__ inline unsigned enc2(float a, float b) {
#if __has_builtin(__builtin_amdgcn_cvt_pk_fp8_f32)
    return ((unsigned)__builtin_amdgcn_cvt_pk_fp8_f32(a, b, 0, false)) & 0xFFFFu;
#else
    return enc1_sw(a) | (enc1_sw(b) << 8);
#endif
}

// ---------- fp8 e4m3 decode to fp16 pair ----------
#if __has_builtin(__builtin_amdgcn_cvt_pk_f16_fp8)
#define YSC 1.0f
static __device__ inline h16x2 dec2lo(unsigned v) {
    return __builtin_amdgcn_cvt_pk_f16_fp8((short)v);
}
static __device__ inline h16x2 dec2hi(unsigned v) {
    return __builtin_amdgcn_cvt_pk_f16_fp8((short)(v >> 16));
}
#else
#define YSC 256.0f
// e4m3 bits<<7 placed in fp16 = value/256 exactly (incl. subnormals); /256 folded into W2
static __device__ inline h16x2 dec2lo(unsigned v) {
    unsigned p = __builtin_amdgcn_perm(0u, v, 0x0C010C00u);   // [0,b1,0,b0]
    unsigned h = ((p << 8) & 0x80008000u) | ((p << 7) & 0x3F803F80u);
    return __builtin_bit_cast(h16x2, h);
}
static __device__ inline h16x2 dec2hi(unsigned v) {
    unsigned p = __builtin_amdgcn_perm(0u, v, 0x0C030C02u);   // [0,b3,0,b2]
    unsigned h = ((p << 8) & 0x80008000u) | ((p << 7) & 0x3F803F80u);
    return __builtin_bit_cast(h16x2, h);
}
#endif

static __device__ inline h16x2 reluh(h16x2 v) {
#if __has_builtin(__builtin_elementwise_max)
    h16x2 z = { (_Float16)0.0f, (_Float16)0.0f };
    return __builtin_elementwise_max(v, z);
#else
    unsigned u = __builtin_bit_cast(unsigned, v);
    unsigned m = ((u >> 15) & 0x00010001u) * 0xFFFFu;
    u &= ~m;
    return __builtin_bit_cast(h16x2, u);
#endif
}

static __device__ inline float dot2acc(h16x2 a, h16x2 b, float c) {
#if __has_builtin(__builtin_amdgcn_fdot2)
    return __builtin_amdgcn_fdot2(a, b, c, false);
#else
    return c + (float)a[0] * (float)b[0] + (float)a[1] * (float)b[1];
#endif
}

// ---------------- pack W1 -> bf16 fragment order ----------------
__global__ __launch_bounds__(256) void pack_w1_kernel(
    const float* __restrict__ W1, short* __restrict__ W1F)
{
    int g    = blockIdx.x * 256 + threadIdx.x;   // 0..4095
    int lane = g & 63;
    int c    = (g >> 6) & 3;
    int j    = (g >> 8) & 3;
    int cs   = g >> 10;
    int o    = cs * 64 + j * 16 + (lane & 15);
    int kb   = c * 32 + (lane >> 4) * 8;
    const float* wp = W1 + (size_t)(o & 127) * 256 + (o >> 7) * 128 + kb;
    float4 u0 = *(const float4*)wp;
    float4 u1 = *(const float4*)(wp + 4);
    s16x8 v = { f2bf(u0.x), f2bf(u0.y), f2bf(u0.z), f2bf(u0.w),
                f2bf(u1.x), f2bf(u1.y), f2bf(u1.z), f2bf(u1.w) };
    *(s16x8*)&W1F[(size_t)g * 8] = v;
}

// ---------------- Phase A: per-wave 32 rows x 64 cols, fp8 output ----------------
__global__ __launch_bounds__(64) void precompute_kernel(
    const float* __restrict__ x,    // [N,128]
    const short* __restrict__ W1F,  // packed bf16 fragments
    const float* __restrict__ b1,   // [128]
    unsigned char* __restrict__ Y8, // [N,256] fp8 e4m3
    int N)
{
    __shared__ _Float16 Cw[32 * CWLD];   // 5120 B, wave-private

    const int lane = threadIdx.x;        // single wave
    const int quad = lane >> 4, l15 = lane & 15;
    const int cs   = blockIdx.x;         // col slice: cols cs*64 .. +63
    const int m0   = blockIdx.y * 32;

    // ---- A raw loads first (HBM)
    float4 ar[2][4][2];
    #pragma unroll
    for (int i = 0; i < 2; ++i) {
        int m = m0 + i * 16 + l15; if (m >= N) m = N - 1;
        const float* xp = &x[(size_t)m * D + quad * 8];
        #pragma unroll
        for (int c = 0; c < 4; ++c) {
            ar[i][c][0] = *(const float4*)(xp + c * 32);
            ar[i][c][1] = *(const float4*)(xp + c * 32 + 4);
        }
    }

    // ---- B frags: coalesced 16B/lane from W1F (L2-hot)
    s16x8 bf[4][4];   // [k-chunk][col-tile]
    #pragma unroll
    for (int j = 0; j < 4; ++j)
        #pragma unroll
        for (int c = 0; c < 4; ++c)
            bf[c][j] = *(const s16x8*)&W1F[(size_t)(((cs * 4 + j) * 4 + c) * 64 + lane) * 8];

    // ---- MFMA
    f32x4 acc[2][4] = {};   // [row-tile][col-tile]
    #pragma unroll
    for (int c = 0; c < 4; ++c) {
        s16x8 af[2];
        #pragma unroll
        for (int i = 0; i < 2; ++i)
            af[i] = (s16x8){ f2bf(ar[i][c][0].x), f2bf(ar[i][c][0].y),
                             f2bf(ar[i][c][0].z), f2bf(ar[i][c][0].w),
                             f2bf(ar[i][c][1].x), f2bf(ar[i][c][1].y),
                             f2bf(ar[i][c][1].z), f2bf(ar[i][c][1].w) };
        #pragma unroll
        for (int i = 0; i < 2; ++i)
            #pragma unroll
            for (int j = 0; j < 4; ++j)
                acc[i][j] = __builtin_amdgcn_mfma_f32_16x16x32_bf16(
                    af[i], bf[c][j], acc[i][j], 0, 0, 0);
    }

    // ---- bias (cs<2 -> left half)
    float b1v[4];
    #pragma unroll
    for (int j = 0; j < 4; ++j)
        b1v[j] = (cs < 2) ? b1[cs * 64 + j * 16 + l15] : 0.f;

    // ---- transpose through wave-private LDS
    // C/D layout: col = lane&15, row = quad*4 + reg
    #pragma unroll
    for (int i = 0; i < 2; ++i)
        #pragma unroll
        for (int j = 0; j < 4; ++j)
            #pragma unroll
            for (int r = 0; r < 4; ++r)
                Cw[(i * 16 + quad * 4 + r) * CWLD + j * 16 + l15] =
                    (_Float16)(acc[i][j][r] + b1v[j]);

    __syncthreads();

    // ---- fp8 encode + store: 16 rows/pass, 4 lanes/row, 16B fp8 per lane
    #pragma unroll
    for (int p = 0; p < 2; ++p) {
        int row = p * 16 + (lane >> 2);
        int m   = m0 + row;
        if (m < N) {
            const _Float16* sp = &Cw[row * CWLD + (lane & 3) * 16];
            uint4 ov;
            unsigned dw[4];
            #pragma unroll
            for (int q = 0; q < 4; ++q)
                dw[q] = enc2((float)sp[q*4+0], (float)sp[q*4+1])
                      | (enc2((float)sp[q*4+2], (float)sp[q*4+3]) << 16);
            ov.x = dw[0]; ov.y = dw[1]; ov.z = dw[2]; ov.w = dw[3];
            *(uint4*)&Y8[(size_t)m * 256 + cs * 64 + (lane & 3) * 16] = ov;
        }
    }
}

// ---------------- Phase B: 4 edges per 8-lane group, fp8 gather ----------------
#define EPB 128   // edges per block (256 threads, 32 groups x 4 edges)

__global__ __launch_bounds__(256) void edge_kernel(
    const unsigned char* __restrict__ Y8,  // [N,256] fp8
    const int*           __restrict__ ei,  // [2,E]
    const float*         __restrict__ W2,  // [128]
    const float*         __restrict__ b2,  // [1]
    float*               __restrict__ out, // [E]
    int E)
{
    const int tid = threadIdx.x;
    const int sub = tid & 7;                    // 8 lanes per edge
    const int grp = tid >> 3;                   // 0..31
    const int e0  = blockIdx.x * EPB + grp;

    // W2 pairs for this sub-lane's 16 columns, scaled for the decode path
    h16x2 w2h[8];
    {
        const float* wp = &W2[sub * 16];
        #pragma unroll
        for (int q = 0; q < 8; ++q) {
            float2 f = *(const float2*)(wp + q * 2);
            w2h[q] = (h16x2){ (_Float16)(f.x * YSC), (_Float16)(f.y * YSC) };
        }
    }

    int  ee[4]; bool vv[4]; uint4 L[4], R[4];
    #pragma unroll
    for (int k = 0; k < 4; ++k) {
        ee[k] = e0 + 32 * k;
        vv[k] = (ee[k] < E);
        int src = vv[k] ? ei[ee[k]] : 0;
        int dst = vv[k] ? ei[E + ee[k]] : 0;
        L[k] = *(const uint4*)(Y8 + (size_t)src * 256 + sub * 16);
        R[k] = *(const uint4*)(Y8 + (size_t)dst * 256 + 128 + sub * 16);
    }

    float s[4] = { 0.f, 0.f, 0.f, 0.f };
    #pragma unroll
    for (int k = 0; k < 4; ++k) {
        const unsigned* a = (const unsigned*)&L[k];
        const unsigned* c = (const unsigned*)&R[k];
        #pragma unroll
        for (int d = 0; d < 4; ++d) {
            h16x2 za = reluh(dec2lo(a[d]) + dec2lo(c[d]));
            s[k] = dot2acc(za, w2h[2*d],     s[k]);
            h16x2 zb = reluh(dec2hi(a[d]) + dec2hi(c[d]));
            s[k] = dot2acc(zb, w2h[2*d + 1], s[k]);
        }
    }

    // reduce over the 8 lanes of each edge
    #pragma unroll
    for (int k = 0; k < 4; ++k) {
        s[k] += __shfl_xor(s[k], 1);
        s[k] += __shfl_xor(s[k], 2);
        s[k] += __shfl_xor(s[k], 4);
    }

    if (sub == 0) {
        float bb = b2[0];
        #pragma unroll
        for (int k = 0; k < 4; ++k) {
            if (vv[k]) {
                float t = fmaxf(s[k] + bb, 0.f);
                out[ee[k]] = 1.0f / (1.0f + expf(-t));
            }
        }
    }
}

// ---------------- fallback (fused edge-wise GEMM, fp32 inputs) ----------------
#define BM   128
#define BK   64
#define LDT  72

__global__ __launch_bounds__(256) void decoder_fallback_kernel(
    const float* __restrict__ x, const int* __restrict__ ei,
    const float* __restrict__ W1, const float* __restrict__ b1,
    const float* __restrict__ W2, const float* __restrict__ b2,
    float* __restrict__ out, int E)
{
    __shared__ int   nid[2][BM];
    __shared__ short At[BM * LDT];
    __shared__ short Bt[D * LDT];
    __shared__ float rowsum[BM][2];

    const int tid = threadIdx.x;
    const int e0  = blockIdx.x * BM;
    if (tid < BM) { int e = e0 + tid; nid[0][tid] = (e < E) ? ei[e] : 0; }
    else { int e = e0 + (tid - BM); nid[1][tid - BM] = (e < E) ? ei[E + e] : 0; }

    const int wid = tid >> 6, lane = tid & 63;
    const int wm = wid >> 1, wn = wid & 1;
    const int quad = lane >> 4, l15 = lane & 15;
    const int srow = tid >> 4, scol = (tid & 15) * 4;
    f32x4 acc[4][4] = {};
    __syncthreads();

    for (int t = 0; t < 4; ++t) {
        const int* ids = nid[t >> 1];
        const int kx = (t & 1) * BK, kw = t * BK;
        #pragma unroll
        for (int p = 0; p < 8; ++p) {
            int row = srow + p * 16;
            float4 v = *(const float4*)&x[(size_t)ids[row] * D + kx + scol];
            s16x4 bv = { f2bf(v.x), f2bf(v.y), f2bf(v.z), f2bf(v.w) };
            *(s16x4*)&At[row * LDT + scol] = bv;
        }
        #pragma unroll
        for (int p = 0; p < 8; ++p) {
            int n = srow + p * 16;
            float4 v = *(const float4*)&W1[n * 256 + kw + scol];
            s16x4 bv = { f2bf(v.x), f2bf(v.y), f2bf(v.z), f2bf(v.w) };
            *(s16x4*)&Bt[n * LDT + scol] = bv;
        }
        __syncthreads();
        #pragma unroll
        for (int c = 0; c < 2; ++c) {
            const int kc = c * 32;
            s16x8 af[4], bfr[4];
            #pragma unroll
            for (int i = 0; i < 4; ++i)
                af[i] = *(const s16x8*)&At[(wm*64 + i*16 + l15) * LDT + kc + quad*8];
            #pragma unroll
            for (int j = 0; j < 4; ++j)
                bfr[j] = *(const s16x8*)&Bt[(wn*64 + j*16 + l15) * LDT + kc + quad*8];
            #pragma unroll
            for (int i = 0; i < 4; ++i)
                #pragma unroll
                for (int j = 0; j < 4; ++j)
                    acc[i][j] = __builtin_amdgcn_mfma_f32_16x16x32_bf16(
                        af[i], bfr[j], acc[i][j], 0, 0, 0);
        }
        __syncthreads();
    }
    float b1v[4], w2v[4];
    #pragma unroll
    for (int j = 0; j < 4; ++j) {
        int col = wn*64 + j*16 + l15;
        b1v[j] = b1[col]; w2v[j] = W2[col];
    }
    float psum[16];
    #pragma unroll
    for (int t = 0; t < 16; ++t) psum[t] = 0.f;
    #pragma unroll
    for (int i = 0; i < 4; ++i)
        #pragma unroll
        for (int j = 0; j < 4; ++j)
            #pragma unroll
            for (int r = 0; r < 4; ++r) {
                float c = fmaxf(acc[i][j][r] + b1v[j], 0.f);
                psum[i*4 + r] += c * w2v[j];
            }
    #pragma unroll
    for (int off = 1; off < 16; off <<= 1)
        #pragma unroll
        for (int t = 0; t < 16; ++t)
            psum[t] += __shfl_xor(psum[t], off);
    if (l15 == 0) {
        #pragma unroll
        for (int i = 0; i < 4; ++i)
            #pragma unroll
            for (int r = 0; r < 4; ++r)
                rowsum[wm*64 + i*16 + quad*4 + r][wn] = psum[i*4 + r];
    }
    __syncthreads();
    if (tid < BM) {
        int e = e0 + tid;
        if (e < E) {
            float s = rowsum[tid][0] + rowsum[tid][1] + b2[0];
            s = fmaxf(s, 0.f);
            out[e] = 1.0f / (1.0f + expf(-s));
        }
    }
}

extern "C" void kernel_launch(void* const* d_in, const int* in_sizes, int n_in,
                              void* d_out, int out_size, void* d_ws, size_t ws_size,
                              hipStream_t stream) {
    const float* x  = (const float*)d_in[0];
    const int*   ei = (const int*)d_in[1];
    const float* W1 = (const float*)d_in[2];
    const float* b1 = (const float*)d_in[3];
    const float* W2 = (const float*)d_in[4];
    const float* b2 = (const float*)d_in[5];
    float* out = (float*)d_out;

    int E = in_sizes[1] / 2;
    int N = in_sizes[0] / D;

    size_t y_bytes = (size_t)N * 256;                    // 25.6 MB fp8
    size_t need    = y_bytes + 32768 * sizeof(short);    // + 64 KB W1F
    if (ws_size >= need) {
        unsigned char* Y8  = (unsigned char*)d_ws;
        short*         W1F = (short*)((char*)d_ws + y_bytes);
        pack_w1_kernel<<<16, 256, 0, stream>>>(W1, W1F);
        dim3 gridA(4, (N + 31) / 32);
        precompute_kernel<<<gridA, 64, 0, stream>>>(x, W1F, b1, Y8, N);
        int gridB = (E + EPB - 1) / EPB;
        edge_kernel<<<gridB, 256, 0, stream>>>(Y8, ei, W2, b2, out, E);
    } else {
        int nblocks = (E + BM - 1) / BM;
        decoder_fallback_kernel<<<nblocks, 256, 0, stream>>>(
            x, ei, W1, b1, W2, b2, out, E);
    }
}

// Round 9
// 133.725 us; speedup vs baseline: 1.2703x; 1.1353x over previous
//
#include <hip/hip_runtime.h>
#include <hip/hip_bf16.h>
#include <hip/hip_fp16.h>
#include <math.h>

// Decoder: out[e] = sigmoid(relu( W2 . relu( W1 * [x[src]; x[dst]] + b1 ) + b2 ))
// Factorized: Y[n][0:128] = W1_left*x[n] + b1 ; Y[n][128:256] = W1_right*x[n]
//             out[e] = sigmoid(relu( W2 . relu(Yl[src]+Yr[dst]) + b2 ))
// Y stored fp8 e4m3 (25.6 MB; halves gather + write traffic, R8).
// R9: precompute fuses the 4 col-slices into one 256-thread block over the
//     same 32-node tile; x staged to LDS once -> x fetched once from HBM by
//     construction (R8 FETCH=100MB showed x read 2x: dispatch-adjacent
//     col-slice blocks land on different XCDs/L2s). One barrier, then 4
//     independent per-wave pipelines (W1F B-frags, MFMA, private transpose).

typedef short    s16x4 __attribute__((ext_vector_type(4)));
typedef short    s16x8 __attribute__((ext_vector_type(8)));
typedef float    f32x4 __attribute__((ext_vector_type(4)));
typedef _Float16 h16x2 __attribute__((ext_vector_type(2)));
typedef _Float16 h16x8 __attribute__((ext_vector_type(8)));

#define D    128
#define ALD  136       // x-tile LDS row stride (shorts): 128 + 8 pad
#define CWLD 80        // transpose LDS row stride (shorts)

static __device__ inline short f2bf(float f) {
    unsigned u = __builtin_bit_cast(unsigned, f);
    unsigned r = (u + 0x7FFFu + ((u >> 16) & 1u)) >> 16;
    return (short)r;
}

// ---------- fp8 e4m3 encode (RNE) ----------
static __device__ inline unsigned enc1_sw(float f) {
    f = fminf(fmaxf(f, -448.f), 448.f);
    unsigned short h = __builtin_bit_cast(unsigned short, (_Float16)(f * (1.0f / 256.0f)));
    unsigned s = (h >> 8) & 0x80u;
    unsigned mag = h & 0x7FFFu;
    mag = mag + 0x3Fu + ((mag >> 7) & 1u);        // RNE 10->3 mantissa bits
    return s | ((mag >> 7) & 0x7Fu);
}
static __device__ inline unsigned enc2(float a, float b) {
#if __has_builtin(__builtin_amdgcn_cvt_pk_fp8_f32)
    return ((unsigned)__builtin_amdgcn_cvt_pk_fp8_f32(a, b, 0, false)) & 0xFFFFu;
#else
    return enc1_sw(a) | (enc1_sw(b) << 8);
#endif
}

// ---------- fp8 e4m3 decode to fp16 pair ----------
#if __has_builtin(__builtin_amdgcn_cvt_pk_f16_fp8)
#define YSC 1.0f
static __device__ inline h16x2 dec2lo(unsigned v) {
    return __builtin_amdgcn_cvt_pk_f16_fp8((short)v);
}
static __device__ inline h16x2 dec2hi(unsigned v) {
    return __builtin_amdgcn_cvt_pk_f16_fp8((short)(v >> 16));
}
#else
#define YSC 256.0f
// e4m3 bits<<7 in fp16 = value/256 exactly (incl. subnormals); /256 folded into W2
static __device__ inline h16x2 dec2lo(unsigned v) {
    unsigned p = __builtin_amdgcn_perm(0u, v, 0x0C010C00u);   // [0,b1,0,b0]
    unsigned h = ((p << 8) & 0x80008000u) | ((p << 7) & 0x3F803F80u);
    return __builtin_bit_cast(h16x2, h);
}
static __device__ inline h16x2 dec2hi(unsigned v) {
    unsigned p = __builtin_amdgcn_perm(0u, v, 0x0C030C02u);   // [0,b3,0,b2]
    unsigned h = ((p << 8) & 0x80008000u) | ((p << 7) & 0x3F803F80u);
    return __builtin_bit_cast(h16x2, h);
}
#endif

static __device__ inline h16x2 reluh(h16x2 v) {
#if __has_builtin(__builtin_elementwise_max)
    h16x2 z = { (_Float16)0.0f, (_Float16)0.0f };
    return __builtin_elementwise_max(v, z);
#else
    unsigned u = __builtin_bit_cast(unsigned, v);
    unsigned m = ((u >> 15) & 0x00010001u) * 0xFFFFu;
    u &= ~m;
    return __builtin_bit_cast(h16x2, u);
#endif
}

static __device__ inline float dot2acc(h16x2 a, h16x2 b, float c) {
#if __has_builtin(__builtin_amdgcn_fdot2)
    return __builtin_amdgcn_fdot2(a, b, c, false);
#else
    return c + (float)a[0] * (float)b[0] + (float)a[1] * (float)b[1];
#endif
}

// ---------------- pack W1 -> bf16 fragment order ----------------
__global__ __launch_bounds__(256) void pack_w1_kernel(
    const float* __restrict__ W1, short* __restrict__ W1F)
{
    int g    = blockIdx.x * 256 + threadIdx.x;   // 0..4095
    int lane = g & 63;
    int c    = (g >> 6) & 3;
    int j    = (g >> 8) & 3;
    int cs   = g >> 10;
    int o    = cs * 64 + j * 16 + (lane & 15);
    int kb   = c * 32 + (lane >> 4) * 8;
    const float* wp = W1 + (size_t)(o & 127) * 256 + (o >> 7) * 128 + kb;
    float4 u0 = *(const float4*)wp;
    float4 u1 = *(const float4*)(wp + 4);
    s16x8 v = { f2bf(u0.x), f2bf(u0.y), f2bf(u0.z), f2bf(u0.w),
                f2bf(u1.x), f2bf(u1.y), f2bf(u1.z), f2bf(u1.w) };
    *(s16x8*)&W1F[(size_t)g * 8] = v;
}

// ---------------- Phase A: 4 waves = 4 col-slices of one 32-node tile ----------------
__global__ __launch_bounds__(256) void precompute_kernel(
    const float* __restrict__ x,    // [N,128]
    const short* __restrict__ W1F,  // packed bf16 fragments
    const float* __restrict__ b1,   // [128]
    unsigned char* __restrict__ Y8, // [N,256] fp8 e4m3
    int N)
{
    __shared__ short    At[32 * ALD];        // 8704 B, shared x tile (bf16)
    __shared__ _Float16 Cw[4][32 * CWLD];    // 4 x 5120 B, wave-private transpose

    const int tid  = threadIdx.x;
    const int wid  = tid >> 6;               // wave id = col slice
    const int lane = tid & 63;
    const int quad = lane >> 4, l15 = lane & 15;
    const int m0   = blockIdx.x * 32;
    const int cs   = wid;

    // ---- stage x tile once (coop, 4 float4/thread), fp32 -> bf16
    const int srow = tid >> 3;               // 0..31
    const int sc0  = (tid & 7) * 4;          // float offset
    float4 xv[4];
    {
        int m = m0 + srow; if (m >= N) m = N - 1;
        const float* xp = &x[(size_t)m * D + sc0];
        #pragma unroll
        for (int p = 0; p < 4; ++p)
            xv[p] = *(const float4*)(xp + p * 32);
    }

    // ---- B frags: coalesced 16B/lane from W1F (L2-hot)
    s16x8 bf[4][4];   // [k-chunk][col-tile]
    #pragma unroll
    for (int j = 0; j < 4; ++j)
        #pragma unroll
        for (int c = 0; c < 4; ++c)
            bf[c][j] = *(const s16x8*)&W1F[(size_t)(((cs * 4 + j) * 4 + c) * 64 + lane) * 8];

    #pragma unroll
    for (int p = 0; p < 4; ++p) {
        s16x4 bv = { f2bf(xv[p].x), f2bf(xv[p].y), f2bf(xv[p].z), f2bf(xv[p].w) };
        *(s16x4*)&At[srow * ALD + sc0 + p * 32] = bv;
    }
    __syncthreads();

    // ---- MFMA: per wave, 2 row-tiles x 4 col-tiles x 4 k-chunks
    f32x4 acc[2][4] = {};
    #pragma unroll
    for (int c = 0; c < 4; ++c) {
        const int kc = c * 32;
        s16x8 af[2];
        #pragma unroll
        for (int i = 0; i < 2; ++i)
            af[i] = *(const s16x8*)&At[(i * 16 + l15) * ALD + kc + quad * 8];
        #pragma unroll
        for (int i = 0; i < 2; ++i)
            #pragma unroll
            for (int j = 0; j < 4; ++j)
                acc[i][j] = __builtin_amdgcn_mfma_f32_16x16x32_bf16(
                    af[i], bf[c][j], acc[i][j], 0, 0, 0);
    }

    // ---- bias (cs<2 -> left half of W1 output)
    float b1v[4];
    #pragma unroll
    for (int j = 0; j < 4; ++j)
        b1v[j] = (cs < 2) ? b1[cs * 64 + j * 16 + l15] : 0.f;

    // ---- transpose through wave-private LDS region
    // C/D layout: col = lane&15, row = quad*4 + reg
    _Float16* cw = &Cw[wid][0];
    #pragma unroll
    for (int i = 0; i < 2; ++i)
        #pragma unroll
        for (int j = 0; j < 4; ++j)
            #pragma unroll
            for (int r = 0; r < 4; ++r)
                cw[(i * 16 + quad * 4 + r) * CWLD + j * 16 + l15] =
                    (_Float16)(acc[i][j][r] + b1v[j]);

    __syncthreads();

    // ---- fp8 encode + store: 16 rows/pass, 4 lanes/row, 16B fp8 per lane
    #pragma unroll
    for (int p = 0; p < 2; ++p) {
        int row = p * 16 + (lane >> 2);
        int m   = m0 + row;
        if (m < N) {
            const _Float16* sp = &cw[row * CWLD + (lane & 3) * 16];
            uint4 ov;
            unsigned dw[4];
            #pragma unroll
            for (int q = 0; q < 4; ++q)
                dw[q] = enc2((float)sp[q*4+0], (float)sp[q*4+1])
                      | (enc2((float)sp[q*4+2], (float)sp[q*4+3]) << 16);
            ov.x = dw[0]; ov.y = dw[1]; ov.z = dw[2]; ov.w = dw[3];
            *(uint4*)&Y8[(size_t)m * 256 + cs * 64 + (lane & 3) * 16] = ov;
        }
    }
}

// ---------------- Phase B: 4 edges per 8-lane group, fp8 gather ----------------
#define EPB 128   // edges per block (256 threads, 32 groups x 4 edges)

__global__ __launch_bounds__(256) void edge_kernel(
    const unsigned char* __restrict__ Y8,  // [N,256] fp8
    const int*           __restrict__ ei,  // [2,E]
    const float*         __restrict__ W2,  // [128]
    const float*         __restrict__ b2,  // [1]
    float*               __restrict__ out, // [E]
    int E)
{
    const int tid = threadIdx.x;
    const int sub = tid & 7;                    // 8 lanes per edge
    const int grp = tid >> 3;                   // 0..31
    const int e0  = blockIdx.x * EPB + grp;

    // W2 pairs for this sub-lane's 16 columns, scaled for the decode path
    h16x2 w2h[8];
    {
        const float* wp = &W2[sub * 16];
        #pragma unroll
        for (int q = 0; q < 8; ++q) {
            float2 f = *(const float2*)(wp + q * 2);
            w2h[q] = (h16x2){ (_Float16)(f.x * YSC), (_Float16)(f.y * YSC) };
        }
    }

    int  ee[4]; bool vv[4]; uint4 L[4], R[4];
    #pragma unroll
    for (int k = 0; k < 4; ++k) {
        ee[k] = e0 + 32 * k;
        vv[k] = (ee[k] < E);
        int src = vv[k] ? ei[ee[k]] : 0;
        int dst = vv[k] ? ei[E + ee[k]] : 0;
        L[k] = *(const uint4*)(Y8 + (size_t)src * 256 + sub * 16);
        R[k] = *(const uint4*)(Y8 + (size_t)dst * 256 + 128 + sub * 16);
    }

    float s[4] = { 0.f, 0.f, 0.f, 0.f };
    #pragma unroll
    for (int k = 0; k < 4; ++k) {
        const unsigned* a = (const unsigned*)&L[k];
        const unsigned* c = (const unsigned*)&R[k];
        #pragma unroll
        for (int d = 0; d < 4; ++d) {
            h16x2 za = reluh(dec2lo(a[d]) + dec2lo(c[d]));
            s[k] = dot2acc(za, w2h[2*d],     s[k]);
            h16x2 zb = reluh(dec2hi(a[d]) + dec2hi(c[d]));
            s[k] = dot2acc(zb, w2h[2*d + 1], s[k]);
        }
    }

    #pragma unroll
    for (int k = 0; k < 4; ++k) {
        s[k] += __shfl_xor(s[k], 1);
        s[k] += __shfl_xor(s[k], 2);
        s[k] += __shfl_xor(s[k], 4);
    }

    if (sub == 0) {
        float bb = b2[0];
        #pragma unroll
        for (int k = 0; k < 4; ++k) {
            if (vv[k]) {
                float t = fmaxf(s[k] + bb, 0.f);
                out[ee[k]] = 1.0f / (1.0f + expf(-t));
            }
        }
    }
}

// ---------------- fallback (fused edge-wise GEMM, fp32 inputs) ----------------
#define BM   128
#define BK   64
#define LDT  72

__global__ __launch_bounds__(256) void decoder_fallback_kernel(
    const float* __restrict__ x, const int* __restrict__ ei,
    const float* __restrict__ W1, const float* __restrict__ b1,
    const float* __restrict__ W2, const float* __restrict__ b2,
    float* __restrict__ out, int E)
{
    __shared__ int   nid[2][BM];
    __shared__ short At[BM * LDT];
    __shared__ short Bt[D * LDT];
    __shared__ float rowsum[BM][2];

    const int tid = threadIdx.x;
    const int e0  = blockIdx.x * BM;
    if (tid < BM) { int e = e0 + tid; nid[0][tid] = (e < E) ? ei[e] : 0; }
    else { int e = e0 + (tid - BM); nid[1][tid - BM] = (e < E) ? ei[E + e] : 0; }

    const int wid = tid >> 6, lane = tid & 63;
    const int wm = wid >> 1, wn = wid & 1;
    const int quad = lane >> 4, l15 = lane & 15;
    const int srow = tid >> 4, scol = (tid & 15) * 4;
    f32x4 acc[4][4] = {};
    __syncthreads();

    for (int t = 0; t < 4; ++t) {
        const int* ids = nid[t >> 1];
        const int kx = (t & 1) * BK, kw = t * BK;
        #pragma unroll
        for (int p = 0; p < 8; ++p) {
            int row = srow + p * 16;
            float4 v = *(const float4*)&x[(size_t)ids[row] * D + kx + scol];
            s16x4 bv = { f2bf(v.x), f2bf(v.y), f2bf(v.z), f2bf(v.w) };
            *(s16x4*)&At[row * LDT + scol] = bv;
        }
        #pragma unroll
        for (int p = 0; p < 8; ++p) {
            int n = srow + p * 16;
            float4 v = *(const float4*)&W1[n * 256 + kw + scol];
            s16x4 bv = { f2bf(v.x), f2bf(v.y), f2bf(v.z), f2bf(v.w) };
            *(s16x4*)&Bt[n * LDT + scol] = bv;
        }
        __syncthreads();
        #pragma unroll
        for (int c = 0; c < 2; ++c) {
            const int kc = c * 32;
            s16x8 af[4], bfr[4];
            #pragma unroll
            for (int i = 0; i < 4; ++i)
                af[i] = *(const s16x8*)&At[(wm*64 + i*16 + l15) * LDT + kc + quad*8];
            #pragma unroll
            for (int j = 0; j < 4; ++j)
                bfr[j] = *(const s16x8*)&Bt[(wn*64 + j*16 + l15) * LDT + kc + quad*8];
            #pragma unroll
            for (int i = 0; i < 4; ++i)
                #pragma unroll
                for (int j = 0; j < 4; ++j)
                    acc[i][j] = __builtin_amdgcn_mfma_f32_16x16x32_bf16(
                        af[i], bfr[j], acc[i][j], 0, 0, 0);
        }
        __syncthreads();
    }
    float b1v[4], w2v[4];
    #pragma unroll
    for (int j = 0; j < 4; ++j) {
        int col = wn*64 + j*16 + l15;
        b1v[j] = b1[col]; w2v[j] = W2[col];
    }
    float psum[16];
    #pragma unroll
    for (int t = 0; t < 16; ++t) psum[t] = 0.f;
    #pragma unroll
    for (int i = 0; i < 4; ++i)
        #pragma unroll
        for (int j = 0; j < 4; ++j)
            #pragma unroll
            for (int r = 0; r < 4; ++r) {
                float c = fmaxf(acc[i][j][r] + b1v[j], 0.f);
                psum[i*4 + r] += c * w2v[j];
            }
    #pragma unroll
    for (int off = 1; off < 16; off <<= 1)
        #pragma unroll
        for (int t = 0; t < 16; ++t)
            psum[t] += __shfl_xor(psum[t], off);
    if (l15 == 0) {
        #pragma unroll
        for (int i = 0; i < 4; ++i)
            #pragma unroll
            for (int r = 0; r < 4; ++r)
                rowsum[wm*64 + i*16 + quad*4 + r][wn] = psum[i*4 + r];
    }
    __syncthreads();
    if (tid < BM) {
        int e = e0 + tid;
        if (e < E) {
            float s = rowsum[tid][0] + rowsum[tid][1] + b2[0];
            s = fmaxf(s, 0.f);
            out[e] = 1.0f / (1.0f + expf(-s));
        }
    }
}

extern "C" void kernel_launch(void* const* d_in, const int* in_sizes, int n_in,
                              void* d_out, int out_size, void* d_ws, size_t ws_size,
                              hipStream_t stream) {
    const float* x  = (const float*)d_in[0];
    const int*   ei = (const int*)d_in[1];
    const float* W1 = (const float*)d_in[2];
    const float* b1 = (const float*)d_in[3];
    const float* W2 = (const float*)d_in[4];
    const float* b2 = (const float*)d_in[5];
    float* out = (float*)d_out;

    int E = in_sizes[1] / 2;
    int N = in_sizes[0] / D;

    size_t y_bytes = (size_t)N * 256;                    // 25.6 MB fp8
    size_t need    = y_bytes + 32768 * sizeof(short);    // + 64 KB W1F
    if (ws_size >= need) {
        unsigned char* Y8  = (unsigned char*)d_ws;
        short*         W1F = (short*)((char*)d_ws + y_bytes);
        pack_w1_kernel<<<16, 256, 0, stream>>>(W1, W1F);
        int gridA = (N + 31) / 32;
        precompute_kernel<<<gridA, 256, 0, stream>>>(x, W1F, b1, Y8, N);
        int gridB = (E + EPB - 1) / EPB;
        edge_kernel<<<gridB, 256, 0, stream>>>(Y8, ei, W2, b2, out, E);
    } else {
        int nblocks = (E + BM - 1) / BM;
        decoder_fallback_kernel<<<nblocks, 256, 0, stream>>>(
            x, ei, W1, b1, W2, b2, out, E);
    }
}

// Round 10
// 133.215 us; speedup vs baseline: 1.2751x; 1.0038x over previous
//
#include <hip/hip_runtime.h>
#include <hip/hip_bf16.h>
#include <hip/hip_fp16.h>
#include <math.h>

// Decoder: out[e] = sigmoid(relu( W2 . relu( W1 * [x[src]; x[dst]] + b1 ) + b2 ))
// Factorized: Y[n][0:128] = W1_left*x[n] + b1 ; Y[n][128:256] = W1_right*x[n]
//             out[e] = sigmoid(relu( W2 . relu(Yl[src]+Yr[dst]) + b2 ))
// Y stored fp8 e4m3 (25.6 MB). R9: 4 col-slice waves share one LDS-staged x
// tile (x fetched once). R10: precompute grid-strided over 4 tiles/block with
// software pipelining -- next tile's x loads issued before current tile's
// MFMA, B-frags/b1 hoisted out of the loop, 782 co-resident blocks (one clean
// round). Attacks precompute's ~3 TB/s (vs 6.5 TB/s streaming demonstrated
// by the harness fill) = latency-uncovered, not BW-bound.

typedef short    s16x4 __attribute__((ext_vector_type(4)));
typedef short    s16x8 __attribute__((ext_vector_type(8)));
typedef float    f32x4 __attribute__((ext_vector_type(4)));
typedef _Float16 h16x2 __attribute__((ext_vector_type(2)));
typedef _Float16 h16x8 __attribute__((ext_vector_type(8)));

#define D    128
#define ALD  136       // x-tile LDS row stride (shorts): 128 + 8 pad
#define CWLD 80        // transpose LDS row stride (shorts)

static __device__ inline short f2bf(float f) {
    unsigned u = __builtin_bit_cast(unsigned, f);
    unsigned r = (u + 0x7FFFu + ((u >> 16) & 1u)) >> 16;
    return (short)r;
}

// ---------- fp8 e4m3 encode (RNE) ----------
static __device__ inline unsigned enc1_sw(float f) {
    f = fminf(fmaxf(f, -448.f), 448.f);
    unsigned short h = __builtin_bit_cast(unsigned short, (_Float16)(f * (1.0f / 256.0f)));
    unsigned s = (h >> 8) & 0x80u;
    unsigned mag = h & 0x7FFFu;
    mag = mag + 0x3Fu + ((mag >> 7) & 1u);        // RNE 10->3 mantissa bits
    return s | ((mag >> 7) & 0x7Fu);
}
static __device__ inline unsigned enc2(float a, float b) {
#if __has_builtin(__builtin_amdgcn_cvt_pk_fp8_f32)
    return ((unsigned)__builtin_amdgcn_cvt_pk_fp8_f32(a, b, 0, false)) & 0xFFFFu;
#else
    return enc1_sw(a) | (enc1_sw(b) << 8);
#endif
}

// ---------- fp8 e4m3 decode to fp16 pair ----------
#if __has_builtin(__builtin_amdgcn_cvt_pk_f16_fp8)
#define YSC 1.0f
static __device__ inline h16x2 dec2lo(unsigned v) {
    return __builtin_amdgcn_cvt_pk_f16_fp8((short)v);
}
static __device__ inline h16x2 dec2hi(unsigned v) {
    return __builtin_amdgcn_cvt_pk_f16_fp8((short)(v >> 16));
}
#else
#define YSC 256.0f
// e4m3 bits<<7 in fp16 = value/256 exactly (incl. subnormals); /256 folded into W2
static __device__ inline h16x2 dec2lo(unsigned v) {
    unsigned p = __builtin_amdgcn_perm(0u, v, 0x0C010C00u);   // [0,b1,0,b0]
    unsigned h = ((p << 8) & 0x80008000u) | ((p << 7) & 0x3F803F80u);
    return __builtin_bit_cast(h16x2, h);
}
static __device__ inline h16x2 dec2hi(unsigned v) {
    unsigned p = __builtin_amdgcn_perm(0u, v, 0x0C030C02u);   // [0,b3,0,b2]
    unsigned h = ((p << 8) & 0x80008000u) | ((p << 7) & 0x3F803F80u);
    return __builtin_bit_cast(h16x2, h);
}
#endif

static __device__ inline h16x2 reluh(h16x2 v) {
#if __has_builtin(__builtin_elementwise_max)
    h16x2 z = { (_Float16)0.0f, (_Float16)0.0f };
    return __builtin_elementwise_max(v, z);
#else
    unsigned u = __builtin_bit_cast(unsigned, v);
    unsigned m = ((u >> 15) & 0x00010001u) * 0xFFFFu;
    u &= ~m;
    return __builtin_bit_cast(h16x2, u);
#endif
}

static __device__ inline float dot2acc(h16x2 a, h16x2 b, float c) {
#if __has_builtin(__builtin_amdgcn_fdot2)
    return __builtin_amdgcn_fdot2(a, b, c, false);
#else
    return c + (float)a[0] * (float)b[0] + (float)a[1] * (float)b[1];
#endif
}

// ---------------- pack W1 -> bf16 fragment order ----------------
__global__ __launch_bounds__(256) void pack_w1_kernel(
    const float* __restrict__ W1, short* __restrict__ W1F)
{
    int g    = blockIdx.x * 256 + threadIdx.x;   // 0..4095
    int lane = g & 63;
    int c    = (g >> 6) & 3;
    int j    = (g >> 8) & 3;
    int cs   = g >> 10;
    int o    = cs * 64 + j * 16 + (lane & 15);
    int kb   = c * 32 + (lane >> 4) * 8;
    const float* wp = W1 + (size_t)(o & 127) * 256 + (o >> 7) * 128 + kb;
    float4 u0 = *(const float4*)wp;
    float4 u1 = *(const float4*)(wp + 4);
    s16x8 v = { f2bf(u0.x), f2bf(u0.y), f2bf(u0.z), f2bf(u0.w),
                f2bf(u1.x), f2bf(u1.y), f2bf(u1.z), f2bf(u1.w) };
    *(s16x8*)&W1F[(size_t)g * 8] = v;
}

// ---------------- Phase A: grid-stride, software-pipelined ----------------
__global__ __launch_bounds__(256) void precompute_kernel(
    const float* __restrict__ x,    // [N,128]
    const short* __restrict__ W1F,  // packed bf16 fragments
    const float* __restrict__ b1,   // [128]
    unsigned char* __restrict__ Y8, // [N,256] fp8 e4m3
    int N, int ntiles)
{
    __shared__ short    At[32 * ALD];        // 8704 B, shared x tile (bf16)
    __shared__ _Float16 Cw[4][32 * CWLD];    // 4 x 5120 B, wave-private transpose

    const int tid  = threadIdx.x;
    const int wid  = tid >> 6;               // wave id = col slice
    const int lane = tid & 63;
    const int quad = lane >> 4, l15 = lane & 15;
    const int cs   = wid;

    // ---- hoisted: B frags (coalesced 16B/lane, L2-hot) + bias
    s16x8 bf[4][4];   // [k-chunk][col-tile]
    #pragma unroll
    for (int j = 0; j < 4; ++j)
        #pragma unroll
        for (int c = 0; c < 4; ++c)
            bf[c][j] = *(const s16x8*)&W1F[(size_t)(((cs * 4 + j) * 4 + c) * 64 + lane) * 8];
    float b1v[4];
    #pragma unroll
    for (int j = 0; j < 4; ++j)
        b1v[j] = (cs < 2) ? b1[cs * 64 + j * 16 + l15] : 0.f;

    const int srow = tid >> 3;               // 0..31 (staging row)
    const int sc0  = (tid & 7) * 4;          // float offset
    _Float16* cw = &Cw[wid][0];

    // ---- preload first tile's x rows
    int t = blockIdx.x;
    float4 xv[4];
    if (t < ntiles) {
        int m = t * 32 + srow; if (m >= N) m = N - 1;
        const float* xp = &x[(size_t)m * D + sc0];
        #pragma unroll
        for (int p = 0; p < 4; ++p)
            xv[p] = *(const float4*)(xp + p * 32);
    }

    while (t < ntiles) {
        const int m0 = t * 32;
        const int tn = t + gridDim.x;

        // ---- stage current tile to LDS (fp32 -> bf16)
        #pragma unroll
        for (int p = 0; p < 4; ++p) {
            s16x4 bv = { f2bf(xv[p].x), f2bf(xv[p].y), f2bf(xv[p].z), f2bf(xv[p].w) };
            *(s16x4*)&At[srow * ALD + sc0 + p * 32] = bv;
        }
        __syncthreads();

        // ---- prefetch next tile's x (in flight during MFMA + epilogue)
        if (tn < ntiles) {
            int m = tn * 32 + srow; if (m >= N) m = N - 1;
            const float* xp = &x[(size_t)m * D + sc0];
            #pragma unroll
            for (int p = 0; p < 4; ++p)
                xv[p] = *(const float4*)(xp + p * 32);
        }

        // ---- MFMA: per wave, 2 row-tiles x 4 col-tiles x 4 k-chunks
        f32x4 acc[2][4] = {};
        #pragma unroll
        for (int c = 0; c < 4; ++c) {
            const int kc = c * 32;
            s16x8 af[2];
            #pragma unroll
            for (int i = 0; i < 2; ++i)
                af[i] = *(const s16x8*)&At[(i * 16 + l15) * ALD + kc + quad * 8];
            #pragma unroll
            for (int i = 0; i < 2; ++i)
                #pragma unroll
                for (int j = 0; j < 4; ++j)
                    acc[i][j] = __builtin_amdgcn_mfma_f32_16x16x32_bf16(
                        af[i], bf[c][j], acc[i][j], 0, 0, 0);
        }

        // ---- transpose through wave-private LDS region
        // C/D layout: col = lane&15, row = quad*4 + reg
        #pragma unroll
        for (int i = 0; i < 2; ++i)
            #pragma unroll
            for (int j = 0; j < 4; ++j)
                #pragma unroll
                for (int r = 0; r < 4; ++r)
                    cw[(i * 16 + quad * 4 + r) * CWLD + j * 16 + l15] =
                        (_Float16)(acc[i][j][r] + b1v[j]);

        // ---- fp8 encode + store (wave-private region; same-wave LDS RAW is
        //      ordered by compiler-inserted lgkmcnt)
        #pragma unroll
        for (int p = 0; p < 2; ++p) {
            int row = p * 16 + (lane >> 2);
            int m   = m0 + row;
            if (m < N) {
                const _Float16* sp = &cw[row * CWLD + (lane & 3) * 16];
                uint4 ov;
                unsigned dw[4];
                #pragma unroll
                for (int q = 0; q < 4; ++q)
                    dw[q] = enc2((float)sp[q*4+0], (float)sp[q*4+1])
                          | (enc2((float)sp[q*4+2], (float)sp[q*4+3]) << 16);
                ov.x = dw[0]; ov.y = dw[1]; ov.z = dw[2]; ov.w = dw[3];
                *(uint4*)&Y8[(size_t)m * 256 + cs * 64 + (lane & 3) * 16] = ov;
            }
        }

        __syncthreads();   // all waves done reading At before next staging
        t = tn;
    }
}

// ---------------- Phase B: 4 edges per 8-lane group, fp8 gather ----------------
#define EPB 128   // edges per block (256 threads, 32 groups x 4 edges)

__global__ __launch_bounds__(256) void edge_kernel(
    const unsigned char* __restrict__ Y8,  // [N,256] fp8
    const int*           __restrict__ ei,  // [2,E]
    const float*         __restrict__ W2,  // [128]
    const float*         __restrict__ b2,  // [1]
    float*               __restrict__ out, // [E]
    int E)
{
    const int tid = threadIdx.x;
    const int sub = tid & 7;                    // 8 lanes per edge
    const int grp = tid >> 3;                   // 0..31
    const int e0  = blockIdx.x * EPB + grp;

    // W2 pairs for this sub-lane's 16 columns, scaled for the decode path
    h16x2 w2h[8];
    {
        const float* wp = &W2[sub * 16];
        #pragma unroll
        for (int q = 0; q < 8; ++q) {
            float2 f = *(const float2*)(wp + q * 2);
            w2h[q] = (h16x2){ (_Float16)(f.x * YSC), (_Float16)(f.y * YSC) };
        }
    }

    int  ee[4]; bool vv[4]; uint4 L[4], R[4];
    #pragma unroll
    for (int k = 0; k < 4; ++k) {
        ee[k] = e0 + 32 * k;
        vv[k] = (ee[k] < E);
        int src = vv[k] ? ei[ee[k]] : 0;
        int dst = vv[k] ? ei[E + ee[k]] : 0;
        L[k] = *(const uint4*)(Y8 + (size_t)src * 256 + sub * 16);
        R[k] = *(const uint4*)(Y8 + (size_t)dst * 256 + 128 + sub * 16);
    }

    float s[4] = { 0.f, 0.f, 0.f, 0.f };
    #pragma unroll
    for (int k = 0; k < 4; ++k) {
        const unsigned* a = (const unsigned*)&L[k];
        const unsigned* c = (const unsigned*)&R[k];
        #pragma unroll
        for (int d = 0; d < 4; ++d) {
            h16x2 za = reluh(dec2lo(a[d]) + dec2lo(c[d]));
            s[k] = dot2acc(za, w2h[2*d],     s[k]);
            h16x2 zb = reluh(dec2hi(a[d]) + dec2hi(c[d]));
            s[k] = dot2acc(zb, w2h[2*d + 1], s[k]);
        }
    }

    #pragma unroll
    for (int k = 0; k < 4; ++k) {
        s[k] += __shfl_xor(s[k], 1);
        s[k] += __shfl_xor(s[k], 2);
        s[k] += __shfl_xor(s[k], 4);
    }

    if (sub == 0) {
        float bb = b2[0];
        #pragma unroll
        for (int k = 0; k < 4; ++k) {
            if (vv[k]) {
                float t = fmaxf(s[k] + bb, 0.f);
                out[ee[k]] = 1.0f / (1.0f + expf(-t));
            }
        }
    }
}

// ---------------- fallback (fused edge-wise GEMM, fp32 inputs) ----------------
#define BM   128
#define BK   64
#define LDT  72

__global__ __launch_bounds__(256) void decoder_fallback_kernel(
    const float* __restrict__ x, const int* __restrict__ ei,
    const float* __restrict__ W1, const float* __restrict__ b1,
    const float* __restrict__ W2, const float* __restrict__ b2,
    float* __restrict__ out, int E)
{
    __shared__ int   nid[2][BM];
    __shared__ short At[BM * LDT];
    __shared__ short Bt[D * LDT];
    __shared__ float rowsum[BM][2];

    const int tid = threadIdx.x;
    const int e0  = blockIdx.x * BM;
    if (tid < BM) { int e = e0 + tid; nid[0][tid] = (e < E) ? ei[e] : 0; }
    else { int e = e0 + (tid - BM); nid[1][tid - BM] = (e < E) ? ei[E + e] : 0; }

    const int wid = tid >> 6, lane = tid & 63;
    const int wm = wid >> 1, wn = wid & 1;
    const int quad = lane >> 4, l15 = lane & 15;
    const int srow = tid >> 4, scol = (tid & 15) * 4;
    f32x4 acc[4][4] = {};
    __syncthreads();

    for (int t = 0; t < 4; ++t) {
        const int* ids = nid[t >> 1];
        const int kx = (t & 1) * BK, kw = t * BK;
        #pragma unroll
        for (int p = 0; p < 8; ++p) {
            int row = srow + p * 16;
            float4 v = *(const float4*)&x[(size_t)ids[row] * D + kx + scol];
            s16x4 bv = { f2bf(v.x), f2bf(v.y), f2bf(v.z), f2bf(v.w) };
            *(s16x4*)&At[row * LDT + scol] = bv;
        }
        #pragma unroll
        for (int p = 0; p < 8; ++p) {
            int n = srow + p * 16;
            float4 v = *(const float4*)&W1[n * 256 + kw + scol];
            s16x4 bv = { f2bf(v.x), f2bf(v.y), f2bf(v.z), f2bf(v.w) };
            *(s16x4*)&Bt[n * LDT + scol] = bv;
        }
        __syncthreads();
        #pragma unroll
        for (int c = 0; c < 2; ++c) {
            const int kc = c * 32;
            s16x8 af[4], bfr[4];
            #pragma unroll
            for (int i = 0; i < 4; ++i)
                af[i] = *(const s16x8*)&At[(wm*64 + i*16 + l15) * LDT + kc + quad*8];
            #pragma unroll
            for (int j = 0; j < 4; ++j)
                bfr[j] = *(const s16x8*)&Bt[(wn*64 + j*16 + l15) * LDT + kc + quad*8];
            #pragma unroll
            for (int i = 0; i < 4; ++i)
                #pragma unroll
                for (int j = 0; j < 4; ++j)
                    acc[i][j] = __builtin_amdgcn_mfma_f32_16x16x32_bf16(
                        af[i], bfr[j], acc[i][j], 0, 0, 0);
        }
        __syncthreads();
    }
    float b1v[4], w2v[4];
    #pragma unroll
    for (int j = 0; j < 4; ++j) {
        int col = wn*64 + j*16 + l15;
        b1v[j] = b1[col]; w2v[j] = W2[col];
    }
    float psum[16];
    #pragma unroll
    for (int t = 0; t < 16; ++t) psum[t] = 0.f;
    #pragma unroll
    for (int i = 0; i < 4; ++i)
        #pragma unroll
        for (int j = 0; j < 4; ++j)
            #pragma unroll
            for (int r = 0; r < 4; ++r) {
                float c = fmaxf(acc[i][j][r] + b1v[j], 0.f);
                psum[i*4 + r] += c * w2v[j];
            }
    #pragma unroll
    for (int off = 1; off < 16; off <<= 1)
        #pragma unroll
        for (int t = 0; t < 16; ++t)
            psum[t] += __shfl_xor(psum[t], off);
    if (l15 == 0) {
        #pragma unroll
        for (int i = 0; i < 4; ++i)
            #pragma unroll
            for (int r = 0; r < 4; ++r)
                rowsum[wm*64 + i*16 + quad*4 + r][wn] = psum[i*4 + r];
    }
    __syncthreads();
    if (tid < BM) {
        int e = e0 + tid;
        if (e < E) {
            float s = rowsum[tid][0] + rowsum[tid][1] + b2[0];
            s = fmaxf(s, 0.f);
            out[e] = 1.0f / (1.0f + expf(-s));
        }
    }
}

extern "C" void kernel_launch(void* const* d_in, const int* in_sizes, int n_in,
                              void* d_out, int out_size, void* d_ws, size_t ws_size,
                              hipStream_t stream) {
    const float* x  = (const float*)d_in[0];
    const int*   ei = (const int*)d_in[1];
    const float* W1 = (const float*)d_in[2];
    const float* b1 = (const float*)d_in[3];
    const float* W2 = (const float*)d_in[4];
    const float* b2 = (const float*)d_in[5];
    float* out = (float*)d_out;

    int E = in_sizes[1] / 2;
    int N = in_sizes[0] / D;

    size_t y_bytes = (size_t)N * 256;                    // 25.6 MB fp8
    size_t need    = y_bytes + 32768 * sizeof(short);    // + 64 KB W1F
    if (ws_size >= need) {
        unsigned char* Y8  = (unsigned char*)d_ws;
        short*         W1F = (short*)((char*)d_ws + y_bytes);
        pack_w1_kernel<<<16, 256, 0, stream>>>(W1, W1F);
        int ntiles = (N + 31) / 32;
        int gridA  = (ntiles + 3) / 4;                   // 4 tiles per block
        precompute_kernel<<<gridA, 256, 0, stream>>>(x, W1F, b1, Y8, N, ntiles);
        int gridB = (E + EPB - 1) / EPB;
        edge_kernel<<<gridB, 256, 0, stream>>>(Y8, ei, W2, b2, out, E);
    } else {
        int nblocks = (E + BM - 1) / BM;
        decoder_fallback_kernel<<<nblocks, 256, 0, stream>>>(
            x, ei, W1, b1, W2, b2, out, E);
    }
}